// Round 1
// baseline (46804.114 us; speedup 1.0000x reference)
//
#include <hip/hip_runtime.h>

#define S_LEN 4096
#define BATCH 16
#define HID   256     // H == F == 256
#define GATE4 1024    // 4F

typedef __bf16 bf16x8 __attribute__((ext_vector_type(8)));
typedef float  f32x4  __attribute__((ext_vector_type(4)));

union FragU {
    unsigned short u[8];
    bf16x8 v;
    uint4  q;
};

__device__ __forceinline__ unsigned short f2bf(float f) {
    unsigned u = __builtin_bit_cast(unsigned, f);
    u += 0x7fffu + ((u >> 16) & 1u);
    return (unsigned short)(u >> 16);
}
__device__ __forceinline__ float bf2f(unsigned short s) {
    unsigned u = ((unsigned)s) << 16;
    return __builtin_bit_cast(float, u);
}
__device__ __forceinline__ float sigmoid_f(float x) {
    return 1.f / (1.f + __expf(-x));
}
__device__ __forceinline__ float tanh_f(float x) {
    // 1 - 2/(e^{2x}+1): safe at +/-inf (no inf/inf)
    float e = __expf(2.f * x);
    return 1.f - 2.f / (e + 1.f);
}

// ---------------------------------------------------------------------------
// Kernel 1: xp[d][s][b][j] = (sum_k x[b][t_eff][k] * Wi_d[k][j]) + bias_d[j]
// stored as bf16. M = S*B = 65536 (row r = t*16+b), K = 256, N = 1024 per dir.
// 64x64 tile, BK=32, 256 threads (4 waves, each a 32x32 region).
// ---------------------------------------------------------------------------
__global__ __launch_bounds__(256, 2) void xp_gemm(
    const float* __restrict__ X,       // inputs [B][S][H]
    const float* __restrict__ Wi_fw, const float* __restrict__ b_fw,
    const float* __restrict__ Wi_rv, const float* __restrict__ b_rv,
    unsigned short* __restrict__ xp_fw, unsigned short* __restrict__ xp_rv)
{
    const int dir = blockIdx.z;
    const float* Wi   = dir ? Wi_rv : Wi_fw;
    const float* bias = dir ? b_rv  : b_fw;
    unsigned short* xp = dir ? xp_rv : xp_fw;

    __shared__ unsigned short As[64][40];   // [m][k] bf16, padded pitch
    __shared__ unsigned short Bs[64][40];   // [n][k] bf16 (transposed), padded

    const int tid  = threadIdx.x;
    const int lane = tid & 63;
    const int wid  = tid >> 6;       // 0..3
    const int quad = lane >> 4;      // 0..3
    const int l16  = lane & 15;
    const int wm = wid >> 1, wn = wid & 1;

    const int r0 = blockIdx.x * 64;  // M block
    const int n0 = blockIdx.y * 64;  // N block within 1024

    // staging maps
    const int ai = tid & 63;             // A tile row
    const int ak = (tid >> 6) * 8;       // A k offset {0,8,16,24}
    const int bk = tid >> 3;             // B k row 0..31
    const int bj = (tid & 7) * 8;        // B n offset

    const int r  = r0 + ai;
    const int t  = r >> 4, bb = r & 15;
    const int t_eff = dir ? (S_LEN - 1 - t) : t;
    const float* Arow = X + ((size_t)bb * S_LEN + t_eff) * HID;

    f32x4 acc[2][2];
    #pragma unroll
    for (int i = 0; i < 2; ++i)
        #pragma unroll
        for (int j = 0; j < 2; ++j) { acc[i][j][0]=0.f; acc[i][j][1]=0.f; acc[i][j][2]=0.f; acc[i][j][3]=0.f; }

    for (int kb = 0; kb < HID / 32; ++kb) {
        // stage A (fp32 -> bf16)
        {
            const float* p = Arow + kb * 32 + ak;
            float4 v0 = *(const float4*)p;
            float4 v1 = *(const float4*)(p + 4);
            FragU fu;
            fu.u[0]=f2bf(v0.x); fu.u[1]=f2bf(v0.y); fu.u[2]=f2bf(v0.z); fu.u[3]=f2bf(v0.w);
            fu.u[4]=f2bf(v1.x); fu.u[5]=f2bf(v1.y); fu.u[6]=f2bf(v1.z); fu.u[7]=f2bf(v1.w);
            *(uint4*)&As[ai][ak] = fu.q;
        }
        // stage B transposed
        {
            const float* p = Wi + (size_t)(kb * 32 + bk) * GATE4 + n0 + bj;
            float4 v0 = *(const float4*)p;
            float4 v1 = *(const float4*)(p + 4);
            unsigned short tmp[8] = { f2bf(v0.x), f2bf(v0.y), f2bf(v0.z), f2bf(v0.w),
                                      f2bf(v1.x), f2bf(v1.y), f2bf(v1.z), f2bf(v1.w) };
            #pragma unroll
            for (int jj = 0; jj < 8; ++jj) Bs[bj + jj][bk] = tmp[jj];
        }
        __syncthreads();

        bf16x8 a0 = *(const bf16x8*)&As[wm * 32 + l16][quad * 8];
        bf16x8 a1 = *(const bf16x8*)&As[wm * 32 + 16 + l16][quad * 8];
        bf16x8 B0 = *(const bf16x8*)&Bs[wn * 32 + l16][quad * 8];
        bf16x8 B1 = *(const bf16x8*)&Bs[wn * 32 + 16 + l16][quad * 8];
        acc[0][0] = __builtin_amdgcn_mfma_f32_16x16x32_bf16(a0, B0, acc[0][0], 0, 0, 0);
        acc[0][1] = __builtin_amdgcn_mfma_f32_16x16x32_bf16(a0, B1, acc[0][1], 0, 0, 0);
        acc[1][0] = __builtin_amdgcn_mfma_f32_16x16x32_bf16(a1, B0, acc[1][0], 0, 0, 0);
        acc[1][1] = __builtin_amdgcn_mfma_f32_16x16x32_bf16(a1, B1, acc[1][1], 0, 0, 0);
        __syncthreads();
    }

    // epilogue: add bias, convert, store bf16
    #pragma unroll
    for (int am = 0; am < 2; ++am)
        #pragma unroll
        for (int bn = 0; bn < 2; ++bn) {
            int ncol = n0 + wn * 32 + bn * 16 + l16;
            float bv = bias[ncol];
            #pragma unroll
            for (int rr = 0; rr < 4; ++rr) {
                int rrow = r0 + wm * 32 + am * 16 + quad * 4 + rr;
                float v = acc[am][bn][rr] + bv;
                xp[(size_t)rrow * GATE4 + ncol] = f2bf(v);
            }
        }
}

// ---------------------------------------------------------------------------
// Kernel 2: the recurrence. ONE workgroup per direction (2 WGs total).
// 512 threads = 8 waves; wave wid owns f in [wid*32, wid*32+32) for all 4
// gates. ALL of Wh (256x1024) lives in the WG's registers as MFMA B-frags
// (Bfrag[4][2][8] = 256 VGPRs/lane). h is exchanged through a
// double-buffered LDS tile with ONE raw s_barrier per step — no cross-CU
// traffic, no threadfence, no flag spin. xp for step s+1 is prefetched into
// registers during step s (raw barrier keeps vmcnt in flight across it).
// ---------------------------------------------------------------------------
__global__ __launch_bounds__(512, 2) void lstm_rec(
    const float* __restrict__ Wh_fw, const float* __restrict__ Wh_rv,
    const unsigned short* __restrict__ xp_fw, const unsigned short* __restrict__ xp_rv,
    float* __restrict__ out,            // [B][S][512]
    float* __restrict__ finals)         // c_fw,h_fw,c_rv,h_rv (each 16x256)
{
    const int dir = blockIdx.x;         // 0..1
    const float* Wh = dir ? Wh_rv : Wh_fw;
    const unsigned short* xp = dir ? xp_rv : xp_fw;

    const int tid  = threadIdx.x;
    const int lane = tid & 63;
    const int wid  = tid >> 6;          // 0..7
    const int quad = lane >> 4;
    const int l16  = lane & 15;

    const int fbase = wid * 32;         // dir-local f block of this wave

    __shared__ unsigned short hbuf[2][16][264];   // double-buffered h (bf16)

    // h0 = 0 (only buffer 0 needs init; buffer 1 is fully overwritten)
    for (int i = tid; i < 16 * 264; i += 512) (&hbuf[0][0][0])[i] = 0;

    // Load Wh into B-fragments (one-time): lane holds
    // Wh[k = kt*32 + quad*8 + j][g*256 + fbase + n*16 + l16], j=0..7.
    bf16x8 Bfrag[4][2][8];
    #pragma unroll
    for (int g = 0; g < 4; ++g)
        #pragma unroll
        for (int n = 0; n < 2; ++n) {
            const int col = g * 256 + fbase + n * 16 + l16;
            #pragma unroll
            for (int kt = 0; kt < 8; ++kt) {
                FragU fu;
                #pragma unroll
                for (int j = 0; j < 8; ++j) {
                    int k = kt * 32 + quad * 8 + j;
                    fu.u[j] = f2bf(Wh[(size_t)k * GATE4 + col]);
                }
                Bfrag[g][n][kt] = fu.v;
            }
        }

    float cst[2][4]  = {};
    float hval[2][4] = {};

    // xp prefetch registers (bf16, converted at consume time)
    const size_t lanebase = (size_t)(quad * 4) * GATE4 + fbase + l16;
    unsigned short xpn[4][2][4];
    {
        const unsigned short* xprow = xp + lanebase;   // s = 0
        #pragma unroll
        for (int g = 0; g < 4; ++g)
            #pragma unroll
            for (int n = 0; n < 2; ++n)
                #pragma unroll
                for (int rr = 0; rr < 4; ++rr)
                    xpn[g][n][rr] = xprow[(size_t)rr * GATE4 + g * 256 + n * 16];
    }

    __syncthreads();   // hbuf[0] zeroed

    int p = 0;
    for (int s = 0; s < S_LEN; ++s) {
        // A-fragments from h in LDS: A[m=l16][k = kt*32 + quad*8 + j]
        bf16x8 Afrag[8];
        #pragma unroll
        for (int kt = 0; kt < 8; ++kt)
            Afrag[kt] = *(const bf16x8*)&hbuf[p][l16][kt * 32 + quad * 8];

        f32x4 accg[4][2];
        #pragma unroll
        for (int g = 0; g < 4; ++g)
            #pragma unroll
            for (int n = 0; n < 2; ++n) {
                accg[g][n][0]=0.f; accg[g][n][1]=0.f; accg[g][n][2]=0.f; accg[g][n][3]=0.f;
            }

        #pragma unroll
        for (int kt = 0; kt < 8; ++kt)
            #pragma unroll
            for (int g = 0; g < 4; ++g) {
                accg[g][0] = __builtin_amdgcn_mfma_f32_16x16x32_bf16(Afrag[kt], Bfrag[g][0][kt], accg[g][0], 0, 0, 0);
                accg[g][1] = __builtin_amdgcn_mfma_f32_16x16x32_bf16(Afrag[kt], Bfrag[g][1][kt], accg[g][1], 0, 0, 0);
            }

        // gates (all in registers): lane owns (m = quad*4+rr, f = fbase+n*16+l16)
        unsigned short hb[2][4];
        #pragma unroll
        for (int n = 0; n < 2; ++n)
            #pragma unroll
            for (int rr = 0; rr < 4; ++rr) {
                float zi = accg[0][n][rr] + bf2f(xpn[0][n][rr]);
                float zf = accg[1][n][rr] + bf2f(xpn[1][n][rr]);
                float zg = accg[2][n][rr] + bf2f(xpn[2][n][rr]);
                float zo = accg[3][n][rr] + bf2f(xpn[3][n][rr]);
                float ig = sigmoid_f(zi);
                float fg = sigmoid_f(zf);
                float gg = tanh_f(zg);
                float og = sigmoid_f(zo);
                float c  = fg * cst[n][rr] + ig * gg;
                cst[n][rr]  = c;
                float h  = og * tanh_f(c);
                hval[n][rr] = h;
                hb[n][rr]   = f2bf(h);
            }

        // prefetch xp for s+1 (consumed next iteration; latency hides under
        // the next step's MFMA phase — the raw barrier does NOT drain vmcnt)
        if (s + 1 < S_LEN) {
            const unsigned short* xprow = xp + (size_t)(s + 1) * (BATCH * GATE4) + lanebase;
            #pragma unroll
            for (int g = 0; g < 4; ++g)
                #pragma unroll
                for (int n = 0; n < 2; ++n)
                    #pragma unroll
                    for (int rr = 0; rr < 4; ++rr)
                        xpn[g][n][rr] = xprow[(size_t)rr * GATE4 + g * 256 + n * 16];
        }

        // new h -> other LDS buffer
        #pragma unroll
        for (int n = 0; n < 2; ++n)
            #pragma unroll
            for (int rr = 0; rr < 4; ++rr)
                hbuf[p ^ 1][quad * 4 + rr][fbase + n * 16 + l16] = hb[n][rr];

        // fp32 output write (fire-and-forget global stores)
        {
            const int t_orig = dir ? (S_LEN - 1 - s) : s;
            float* obase = out + (size_t)t_orig * 512 + dir * 256 + fbase + l16;
            #pragma unroll
            for (int n = 0; n < 2; ++n)
                #pragma unroll
                for (int rr = 0; rr < 4; ++rr)
                    obase[(size_t)(quad * 4 + rr) * S_LEN * 512 + n * 16] = hval[n][rr];
        }

        // producer barrier: LDS writes must land (lgkmcnt), but global loads/
        // stores stay in flight (NO vmcnt drain — that's why this is not
        // __syncthreads()).
        asm volatile("s_waitcnt lgkmcnt(0)" ::: "memory");
        __builtin_amdgcn_s_barrier();

        p ^= 1;
    }

    // final states: c then h, fw block then rv block
    {
        float* cdst = finals + (dir ? 8192 : 0);
        float* hdst = cdst + 4096;
        #pragma unroll
        for (int n = 0; n < 2; ++n)
            #pragma unroll
            for (int rr = 0; rr < 4; ++rr) {
                int m = quad * 4 + rr;
                int f = fbase + n * 16 + l16;
                cdst[m * 256 + f] = cst[n][rr];
                hdst[m * 256 + f] = hval[n][rr];
            }
    }
}

// ---------------------------------------------------------------------------
extern "C" void kernel_launch(void* const* d_in, const int* in_sizes, int n_in,
                              void* d_out, int out_size, void* d_ws, size_t ws_size,
                              hipStream_t stream)
{
    const float* X     = (const float*)d_in[0];
    const float* Wi_fw = (const float*)d_in[1];
    const float* Wh_fw = (const float*)d_in[2];
    const float* b_fw  = (const float*)d_in[3];
    const float* Wi_rv = (const float*)d_in[4];
    const float* Wh_rv = (const float*)d_in[5];
    const float* b_rv  = (const float*)d_in[6];

    float* out    = (float*)d_out;
    float* finals = out + (size_t)BATCH * S_LEN * 512;

    char* ws = (char*)d_ws;
    unsigned short* xp_fw = (unsigned short*)ws;                          // 128 MiB
    unsigned short* xp_rv = (unsigned short*)(ws + 134217728ull);         // 128 MiB

    dim3 g(65536 / 64, 1024 / 64, 2);
    xp_gemm<<<g, 256, 0, stream>>>(X, Wi_fw, b_fw, Wi_rv, b_rv, xp_fw, xp_rv);

    lstm_rec<<<2, 512, 0, stream>>>(Wh_fw, Wh_rv, xp_fw, xp_rv, out, finals);
}

// Round 3
// 13322.493 us; speedup vs baseline: 3.5132x; 3.5132x over previous
//
#include <hip/hip_runtime.h>

#define S_LEN 4096
#define BATCH 16
#define HID   256     // H == F == 256
#define GATE4 1024    // 4F

typedef __bf16 bf16x8 __attribute__((ext_vector_type(8)));
typedef float  f32x4  __attribute__((ext_vector_type(4)));

union FragU {
    unsigned short u[8];
    bf16x8 v;
    uint4  q;
};

__device__ __forceinline__ unsigned short f2bf(float f) {
    unsigned u = __builtin_bit_cast(unsigned, f);
    u += 0x7fffu + ((u >> 16) & 1u);
    return (unsigned short)(u >> 16);
}
__device__ __forceinline__ float bf2f(unsigned short s) {
    unsigned u = ((unsigned)s) << 16;
    return __builtin_bit_cast(float, u);
}
__device__ __forceinline__ float sigmoid_f(float x) {
    return 1.f / (1.f + __expf(-x));
}
__device__ __forceinline__ float tanh_f(float x) {
    float e = __expf(2.f * x);
    return 1.f - 2.f / (e + 1.f);
}

// ---------------------------------------------------------------------------
// Kernel 0: init control block.
// ctrl[0/32/64/96] = seq flags per role. ctrl[8..15] = per-XCD claim
// counters. ctrl[16] = winner XCD (0xFFFFFFFF = undecided).
// ---------------------------------------------------------------------------
__global__ void init_ctrl(unsigned int* c) {
    if (threadIdx.x < 128) c[threadIdx.x] = (threadIdx.x == 16) ? 0xFFFFFFFFu : 0u;
}

// ---------------------------------------------------------------------------
// Kernel 1: xp gemm (unchanged — not the bottleneck)
// ---------------------------------------------------------------------------
__global__ __launch_bounds__(256, 2) void xp_gemm(
    const float* __restrict__ X,
    const float* __restrict__ Wi_fw, const float* __restrict__ b_fw,
    const float* __restrict__ Wi_rv, const float* __restrict__ b_rv,
    unsigned short* __restrict__ xp_fw, unsigned short* __restrict__ xp_rv)
{
    const int dir = blockIdx.z;
    const float* Wi   = dir ? Wi_rv : Wi_fw;
    const float* bias = dir ? b_rv  : b_fw;
    unsigned short* xp = dir ? xp_rv : xp_fw;

    __shared__ unsigned short As[64][40];
    __shared__ unsigned short Bs[64][40];

    const int tid  = threadIdx.x;
    const int lane = tid & 63;
    const int wid  = tid >> 6;
    const int quad = lane >> 4;
    const int l16  = lane & 15;
    const int wm = wid >> 1, wn = wid & 1;

    const int r0 = blockIdx.x * 64;
    const int n0 = blockIdx.y * 64;

    const int ai = tid & 63;
    const int ak = (tid >> 6) * 8;
    const int bk = tid >> 3;
    const int bj = (tid & 7) * 8;

    const int r  = r0 + ai;
    const int t  = r >> 4, bb = r & 15;
    const int t_eff = dir ? (S_LEN - 1 - t) : t;
    const float* Arow = X + ((size_t)bb * S_LEN + t_eff) * HID;

    f32x4 acc[2][2];
    #pragma unroll
    for (int i = 0; i < 2; ++i)
        #pragma unroll
        for (int j = 0; j < 2; ++j) { acc[i][j][0]=0.f; acc[i][j][1]=0.f; acc[i][j][2]=0.f; acc[i][j][3]=0.f; }

    for (int kb = 0; kb < HID / 32; ++kb) {
        {
            const float* p = Arow + kb * 32 + ak;
            float4 v0 = *(const float4*)p;
            float4 v1 = *(const float4*)(p + 4);
            FragU fu;
            fu.u[0]=f2bf(v0.x); fu.u[1]=f2bf(v0.y); fu.u[2]=f2bf(v0.z); fu.u[3]=f2bf(v0.w);
            fu.u[4]=f2bf(v1.x); fu.u[5]=f2bf(v1.y); fu.u[6]=f2bf(v1.z); fu.u[7]=f2bf(v1.w);
            *(uint4*)&As[ai][ak] = fu.q;
        }
        {
            const float* p = Wi + (size_t)(kb * 32 + bk) * GATE4 + n0 + bj;
            float4 v0 = *(const float4*)p;
            float4 v1 = *(const float4*)(p + 4);
            unsigned short tmp[8] = { f2bf(v0.x), f2bf(v0.y), f2bf(v0.z), f2bf(v0.w),
                                      f2bf(v1.x), f2bf(v1.y), f2bf(v1.z), f2bf(v1.w) };
            #pragma unroll
            for (int jj = 0; jj < 8; ++jj) Bs[bj + jj][bk] = tmp[jj];
        }
        __syncthreads();

        bf16x8 a0 = *(const bf16x8*)&As[wm * 32 + l16][quad * 8];
        bf16x8 a1 = *(const bf16x8*)&As[wm * 32 + 16 + l16][quad * 8];
        bf16x8 B0 = *(const bf16x8*)&Bs[wn * 32 + l16][quad * 8];
        bf16x8 B1 = *(const bf16x8*)&Bs[wn * 32 + 16 + l16][quad * 8];
        acc[0][0] = __builtin_amdgcn_mfma_f32_16x16x32_bf16(a0, B0, acc[0][0], 0, 0, 0);
        acc[0][1] = __builtin_amdgcn_mfma_f32_16x16x32_bf16(a0, B1, acc[0][1], 0, 0, 0);
        acc[1][0] = __builtin_amdgcn_mfma_f32_16x16x32_bf16(a1, B0, acc[1][0], 0, 0, 0);
        acc[1][1] = __builtin_amdgcn_mfma_f32_16x16x32_bf16(a1, B1, acc[1][1], 0, 0, 0);
        __syncthreads();
    }

    #pragma unroll
    for (int am = 0; am < 2; ++am)
        #pragma unroll
        for (int bn = 0; bn < 2; ++bn) {
            int ncol = n0 + wn * 32 + bn * 16 + l16;
            float bv = bias[ncol];
            #pragma unroll
            for (int rr = 0; rr < 4; ++rr) {
                int rrow = r0 + wm * 32 + am * 16 + quad * 4 + rr;
                float v = acc[am][bn][rr] + bv;
                xp[(size_t)rrow * GATE4 + ncol] = f2bf(v);
            }
        }
}

// ---------------------------------------------------------------------------
// Kernel 2: recurrence. 64 WGs; runtime election picks 4 WGs on ONE XCD
// (roles assigned by actual HW_REG_XCC_ID — correctness never depends on
// dispatch mapping). Exchange protocol: relaxed agent-scope atomics only
// (no fences, no acquire/buffer_inv, no threadfence). Ordering: data stores
// acked (vmcnt 0) before flag store; reader observes flag then loads data.
// ---------------------------------------------------------------------------
__global__ __launch_bounds__(512, 2) void lstm_rec(
    const float* __restrict__ Wh_fw, const float* __restrict__ Wh_rv,
    const unsigned short* __restrict__ xp_fw, const unsigned short* __restrict__ xp_rv,
    float* __restrict__ out,            // [B][S][512]
    float* __restrict__ finals,         // c_fw,h_fw,c_rv,h_rv (each 16x256)
    unsigned short* __restrict__ exch,  // [dir][parity][half] x [128 cols][16 rows] bf16
    unsigned int* __restrict__ ctrl)
{
    const int tid  = threadIdx.x;
    __shared__ int role_s;

    // ---- XCD claim: elect 4 co-XCD workgroups ----
    if (tid == 0) {
        unsigned xcc;
        asm volatile("s_getreg_b32 %0, hwreg(HW_REG_XCC_ID)" : "=s"(xcc));
        xcc &= 7u;
        int role = -1;
        unsigned idx = atomicAdd(&ctrl[8u + xcc], 1u);
        if (idx < 4u) {
            if (idx == 3u) atomicCAS(&ctrl[16], 0xFFFFFFFFu, xcc);
            // spin via RMW (always performed at the coherence point — a
            // relaxed LOAD here can read a stale L2 line forever)
            unsigned w;
            while ((w = __hip_atomic_fetch_add(&ctrl[16], 0u, __ATOMIC_RELAXED,
                                               __HIP_MEMORY_SCOPE_AGENT)) == 0xFFFFFFFFu)
                __builtin_amdgcn_s_sleep(2);
            if (w == xcc) role = (int)idx;
        }
        role_s = role;
    }
    __syncthreads();
    const int role = role_s;
    if (role < 0) return;               // uniform per WG

    const int dir  = role >> 1;
    const int half = role & 1;
    const float* Wh = dir ? Wh_rv : Wh_fw;
    const unsigned short* xp = dir ? xp_rv : xp_fw;

    const int lane = tid & 63;
    const int wid  = tid >> 6;          // 0..7
    const int quad = lane >> 4;
    const int l16  = lane & 15;

    const int fbase = half * 128 + wid * 16;   // dir-local f of this wave
    const int floc  = wid * 16 + l16;          // half-local f (0..127)
    const int po    = (1 - half) * 128;        // partner's column base in hbuf

    __shared__ unsigned short hbuf[16][264];   // full h (bf16), padded pitch

    for (int i = tid; i < 16 * 264; i += 512) ((unsigned short*)hbuf)[i] = 0;

    // Wh half -> B-fragments (one-time)
    bf16x8 Bfrag[4][8];
    #pragma unroll
    for (int g = 0; g < 4; ++g) {
        int col = g * 256 + fbase + l16;
        #pragma unroll
        for (int kt = 0; kt < 8; ++kt) {
            FragU fu;
            #pragma unroll
            for (int j = 0; j < 8; ++j) {
                int k = kt * 32 + quad * 8 + j;
                fu.u[j] = f2bf(Wh[(size_t)k * GATE4 + col]);
            }
            Bfrag[g][kt] = fu.v;
        }
    }

    float cst[4]  = {0.f, 0.f, 0.f, 0.f};
    float hval[4] = {0.f, 0.f, 0.f, 0.f};

    unsigned int* myseq = ctrl + (dir * 2 + half) * 32;
    unsigned int* pseq  = ctrl + (dir * 2 + (1 - half)) * 32;

    const size_t lanebase = (size_t)(quad * 4) * GATE4 + fbase + l16;

    // xp register sets: xpA = xp[s even], xpB = xp[s odd]; refetched 2 ahead
    unsigned short xpA[4][4], xpB[4][4];
    {
        const unsigned short* x0 = xp + lanebase;
        const unsigned short* x1 = xp + (size_t)BATCH * GATE4 + lanebase;
        #pragma unroll
        for (int g = 0; g < 4; ++g)
            #pragma unroll
            for (int rr = 0; rr < 4; ++rr) {
                xpA[g][rr] = x0[(size_t)rr * GATE4 + g * 256];
                xpB[g][rr] = x1[(size_t)rr * GATE4 + g * 256];
            }
    }

    // partner-read map: thread handles column c (of partner half), rows g4*4..+3
    const int prc = tid & 127;          // partner col
    const int pg4 = tid >> 7;           // row group 0..3

    __syncthreads();   // hbuf zeroed

    auto step = [&](int s, unsigned short (&xpc)[4][4]) {
        const int parity = s & 1;
        const bool last = (s == S_LEN - 1);

        // 1. A-fragments from full h
        bf16x8 Afrag[8];
        #pragma unroll
        for (int kt = 0; kt < 8; ++kt)
            Afrag[kt] = *(const bf16x8*)&hbuf[l16][kt * 32 + quad * 8];

        // 2. reads done -> hbuf may be overwritten after this barrier
        asm volatile("s_waitcnt lgkmcnt(0)" ::: "memory");
        __builtin_amdgcn_s_barrier();                       // A

        // 3. MFMA
        f32x4 accg[4];
        #pragma unroll
        for (int g = 0; g < 4; ++g) { accg[g][0]=0.f; accg[g][1]=0.f; accg[g][2]=0.f; accg[g][3]=0.f; }
        #pragma unroll
        for (int kt = 0; kt < 8; ++kt) {
            accg[0] = __builtin_amdgcn_mfma_f32_16x16x32_bf16(Afrag[kt], Bfrag[0][kt], accg[0], 0, 0, 0);
            accg[1] = __builtin_amdgcn_mfma_f32_16x16x32_bf16(Afrag[kt], Bfrag[1][kt], accg[1], 0, 0, 0);
            accg[2] = __builtin_amdgcn_mfma_f32_16x16x32_bf16(Afrag[kt], Bfrag[2][kt], accg[2], 0, 0, 0);
            accg[3] = __builtin_amdgcn_mfma_f32_16x16x32_bf16(Afrag[kt], Bfrag[3][kt], accg[3], 0, 0, 0);
        }

        // 4. gates
        unsigned short hb[4];
        #pragma unroll
        for (int rr = 0; rr < 4; ++rr) {
            float zi = accg[0][rr] + bf2f(xpc[0][rr]);
            float zf = accg[1][rr] + bf2f(xpc[1][rr]);
            float zg = accg[2][rr] + bf2f(xpc[2][rr]);
            float zo = accg[3][rr] + bf2f(xpc[3][rr]);
            float ig = sigmoid_f(zi);
            float fg = sigmoid_f(zf);
            float gg = tanh_f(zg);
            float og = sigmoid_f(zo);
            float c  = fg * cst[rr] + ig * gg;
            cst[rr]  = c;
            float h  = og * tanh_f(c);
            hval[rr] = h;
            hb[rr]   = f2bf(h);
        }

        // 5. own half -> LDS
        #pragma unroll
        for (int rr = 0; rr < 4; ++rr)
            hbuf[quad * 4 + rr][fbase + l16] = hb[rr];

        if (!last) {
            // 6. publish own half: one 8B relaxed agent atomic store per thread
            unsigned long long pk =
                  (unsigned long long)hb[0]
                | ((unsigned long long)hb[1] << 16)
                | ((unsigned long long)hb[2] << 32)
                | ((unsigned long long)hb[3] << 48);
            unsigned long long* ex = (unsigned long long*)(exch
                + (size_t)(((dir * 2 + parity) * 2) + half) * 2048)
                + ((size_t)floc * 16 + quad * 4) / 4;
            __hip_atomic_store(ex, pk, __ATOMIC_RELAXED, __HIP_MEMORY_SCOPE_AGENT);
            asm volatile("s_waitcnt vmcnt(0)" ::: "memory");   // acked at coherence point
            __builtin_amdgcn_s_barrier();                      // B: all waves' stores acked
            if (tid == 0)
                __hip_atomic_store(myseq, (unsigned)(s + 1), __ATOMIC_RELAXED,
                                   __HIP_MEMORY_SCOPE_AGENT);

            // 7. all-lane poll (relaxed; per-lane observation orders per-lane loads)
            while (__hip_atomic_load(pseq, __ATOMIC_RELAXED, __HIP_MEMORY_SCOPE_AGENT)
                   < (unsigned)(s + 1)) { }
            asm volatile("" ::: "memory");   // no compiler reordering across the poll

            // 8. partner half -> LDS (8B relaxed agent load per thread)
            const unsigned long long* pd = (const unsigned long long*)(exch
                + (size_t)(((dir * 2 + parity) * 2) + (1 - half)) * 2048)
                + ((size_t)prc * 16 + pg4 * 4) / 4;
            unsigned long long v = __hip_atomic_load(pd, __ATOMIC_RELAXED,
                                                     __HIP_MEMORY_SCOPE_AGENT);
            hbuf[pg4 * 4 + 0][po + prc] = (unsigned short)(v);
            hbuf[pg4 * 4 + 1][po + prc] = (unsigned short)(v >> 16);
            hbuf[pg4 * 4 + 2][po + prc] = (unsigned short)(v >> 32);
            hbuf[pg4 * 4 + 3][po + prc] = (unsigned short)(v >> 48);
            asm volatile("s_waitcnt lgkmcnt(0)" ::: "memory");
            __builtin_amdgcn_s_barrier();                      // D: full h ready
        }

        // 9. out stores (fire & forget) + xp refetch 2 ahead
        {
            int t_orig = dir ? (S_LEN - 1 - s) : s;
            float* ob = out + (size_t)t_orig * 512 + dir * 256 + fbase + l16;
            #pragma unroll
            for (int rr = 0; rr < 4; ++rr)
                ob[(size_t)(quad * 4 + rr) * S_LEN * 512] = hval[rr];
        }
        if (s + 2 < S_LEN) {
            const unsigned short* xr = xp + (size_t)(s + 2) * (BATCH * GATE4) + lanebase;
            #pragma unroll
            for (int g = 0; g < 4; ++g)
                #pragma unroll
                for (int rr = 0; rr < 4; ++rr)
                    xpc[g][rr] = xr[(size_t)rr * GATE4 + g * 256];
        }
    };

    for (int s2 = 0; s2 < S_LEN; s2 += 2) {
        step(s2,     xpA);
        step(s2 + 1, xpB);
    }

    // final states: c then h, fw block then rv block
    {
        float* cdst = finals + (dir ? 8192 : 0);
        float* hdst = cdst + 4096;
        #pragma unroll
        for (int rr = 0; rr < 4; ++rr) {
            int m = quad * 4 + rr;
            int f = fbase + l16;
            cdst[m * 256 + f] = cst[rr];
            hdst[m * 256 + f] = hval[rr];
        }
    }
}

// ---------------------------------------------------------------------------
extern "C" void kernel_launch(void* const* d_in, const int* in_sizes, int n_in,
                              void* d_out, int out_size, void* d_ws, size_t ws_size,
                              hipStream_t stream)
{
    const float* X     = (const float*)d_in[0];
    const float* Wi_fw = (const float*)d_in[1];
    const float* Wh_fw = (const float*)d_in[2];
    const float* b_fw  = (const float*)d_in[3];
    const float* Wi_rv = (const float*)d_in[4];
    const float* Wh_rv = (const float*)d_in[5];
    const float* b_rv  = (const float*)d_in[6];

    float* out    = (float*)d_out;
    float* finals = out + (size_t)BATCH * S_LEN * 512;

    char* ws = (char*)d_ws;
    unsigned short* xp_fw = (unsigned short*)ws;                          // 128 MiB
    unsigned short* xp_rv = (unsigned short*)(ws + 134217728ull);         // 128 MiB
    unsigned short* exch  = (unsigned short*)(ws + 268435456ull);         // 32 KiB
    unsigned int*   ctrl  = (unsigned int*)(ws + 268435456ull + 32768ull);// 512 B

    init_ctrl<<<1, 128, 0, stream>>>(ctrl);

    dim3 g(65536 / 64, 1024 / 64, 2);
    xp_gemm<<<g, 256, 0, stream>>>(X, Wi_fw, b_fw, Wi_rv, b_rv, xp_fw, xp_rv);

    lstm_rec<<<64, 512, 0, stream>>>(Wh_fw, Wh_rv, xp_fw, xp_rv, out, finals, exch, ctrl);
}